// Round 7
// baseline (987.842 us; speedup 1.0000x reference)
//
#include <hip/hip_runtime.h>
#include <hip/hip_bf16.h>

typedef short short8 __attribute__((ext_vector_type(8)));
typedef float f32x4 __attribute__((ext_vector_type(4)));
typedef float f32x2 __attribute__((ext_vector_type(2)));
typedef unsigned short u16;
typedef unsigned int u32;
typedef u32 u32x4 __attribute__((ext_vector_type(4)));

#define NL_STRIDE 57344
#define OFF_W1F 0
#define OFF_W2F 16384
#define OFF_W3F 49152
#define OFF_W1K 53248
#define OFF_B1  54272
#define OFF_B2  54784
#define OFF_B3  55296

__device__ __forceinline__ u16 f2bf(float f) {
  union { float f; unsigned int u; } v; v.f = f;
  unsigned int r = v.u + 0x7fffu + ((v.u >> 16) & 1u);
  return (u16)(r >> 16);
}

// packed f32x2 -> packed bf16 (RNE via MODE default). Scalar srcs: any two VGPRs.
__device__ __forceinline__ u32 cvt_pk_bf16(float lo, float hi) {
  u32 r;
  asm("v_cvt_pk_bf16_f32 %0, %1, %2" : "=v"(r) : "v"(lo), "v"(hi));
  return r;
}

__device__ __forceinline__ f32x2 bc2(float s) { return (f32x2){s, s}; }

// gelu(x) = x * Phi_approx(x); Phi ~ 0.5 + x*(p0 + p1*x^2 + p2*x^4), clamped to [0,1].
// f32x2 form lowers to v_pk_fma_f32 / v_pk_mul_f32 on gfx950.
__device__ __forceinline__ f32x2 gelu2(f32x2 x) {
  f32x2 u = x * x;
  f32x2 t = u * 0.00417617f + (-0.0560330f);
  t = t * u + 0.394326f;
  f32x2 s = x * t + 0.5f;
  s.x = __builtin_amdgcn_fmed3f(s.x, 0.0f, 1.0f);
  s.y = __builtin_amdgcn_fmed3f(s.y, 0.0f, 1.0f);
  return x * s;
}

// hid column permutation for the M-split wave decomposition: each wave owns a
// 64-col group (nq) of 4 n-tiles; pairs (c, c+16) within each 32-col half-group
// sit adjacently so the epilogue emits one cvt_pk + one ds_write_b32 per 2 elems.
// Position p holds original column c(p):
//   nq=p>>6, g=(p>>5)&1, lr=(p>>1)&15, hi=p&1  ->  c = nq*64 + (g*2+hi)*16 + lr
__device__ __forceinline__ int perm_col(int p) {
  return (p & ~63) | (((p >> 5) & 1) << 5) | ((p & 1) << 4) | ((p >> 1) & 15);
}

// ---------------- prep: swizzle fp32 weights -> bf16 MFMA B-fragment order in ws ----
// B-frag layout for mfma_f32_16x16x32_bf16, tile (kt,nt): lane l holds
// B[kt*32 + (l>>4)*8 + j][nt*16 + (l&15)], j=0..7; flat elem = (kt*NT+nt)*512 + l*8 + j.
// W2/W3 K-rows are stored permuted (perm_col) to match the permuted hid layout.
__global__ __launch_bounds__(256) void prep_kernel(
    const float* __restrict__ sW1, const float* __restrict__ sb1,
    const float* __restrict__ sW2, const float* __restrict__ sb2,
    const float* __restrict__ sW3, const float* __restrict__ sb3,
    const float* __restrict__ tW1, const float* __restrict__ tb1,
    const float* __restrict__ tW2, const float* __restrict__ tb2,
    const float* __restrict__ tW3, const float* __restrict__ tb3,
    char* __restrict__ ws)
{
  int nl = blockIdx.x;               // 0..7 = layer*2 + net
  int layer = nl >> 1, net = nl & 1;
  const float* W1 = net ? tW1 : sW1;
  const float* W2 = net ? tW2 : sW2;
  const float* W3 = net ? tW3 : sW3;
  const float* B1 = net ? tb1 : sb1;
  const float* B2 = net ? tb2 : sb2;
  const float* B3 = net ? tb3 : sb3;
  char* base = ws + (size_t)nl * NL_STRIDE;
  int e = blockIdx.y * 256 + (int)threadIdx.x;

  if (e < 8192) {                                   // W1 (h-rows 2..65): K=64, N=128
    int kt = e >> 12, rem = e & 4095, nt = rem >> 9, r2 = rem & 511;
    int l = r2 >> 3, j = r2 & 7;
    int k = kt * 32 + (l >> 4) * 8 + j, n = nt * 16 + (l & 15);
    ((u16*)(base + OFF_W1F))[e] = f2bf(W1[layer * 8448 + (2 + k) * 128 + n]);
  } else if (e < 24576) {                           // W2: K=128 (perm rows), N=128
    int e2 = e - 8192;
    int kt = e2 >> 12, nt = (e2 >> 9) & 7, l = (e2 >> 3) & 63, j = e2 & 7;
    int kp = kt * 32 + (l >> 4) * 8 + j, n = nt * 16 + (l & 15);
    int c = perm_col(kp);
    ((u16*)(base + OFF_W2F))[e2] = f2bf(W2[layer * 16384 + c * 128 + n]);
  } else if (e < 26624) {                           // W3: K=128 (perm rows), N padded 2->16
    int e3 = e - 24576;
    int kt = e3 >> 9, l = (e3 >> 3) & 63, j = e3 & 7;
    int kp = kt * 32 + (l >> 4) * 8 + j, n = l & 15;
    int c = perm_col(kp);
    float v = (n < 2) ? W3[layer * 256 + c * 2 + n] : 0.0f;
    ((u16*)(base + OFF_W3F))[e3] = f2bf(v);
  } else if (e < 26880) {                           // W1 keep-rows 0..1 as fp32 [2][128]
    int e4 = e - 26624; int r = e4 >> 7, n = e4 & 127;
    ((float*)(base + OFF_W1K))[e4] = W1[layer * 8448 + r * 128 + n];
  } else if (e < 27008) {
    int e5 = e - 26880; ((float*)(base + OFF_B1))[e5] = B1[layer * 128 + e5];
  } else if (e < 27136) {
    int e6 = e - 27008; ((float*)(base + OFF_B2))[e6] = B2[layer * 128 + e6];
  } else if (e < 27138) {
    int e7 = e - 27136; ((float*)(base + OFF_B3))[e7] = B3[layer * 2 + e7];
  }
}

// ---------------- main fused kernel: 64 rows/block, 256 threads (4 waves) -----------
// R3 structure + M-SPLIT wave decomposition: wave wv = (mhalf, nq) computes the
// 32-row half mhalf over 4 n-tiles (nq*64..+63). This halves per-wave LDS A-frag
// reads (28 -> 16 ds_read_b128 per wave per net) -- the shared per-CU LDS pipe is
// the bottleneck (~58% busy in the R3 cycle model); B-frag reads shift to L2.
// LDS 27136 B, launch_bounds (256,5): 5 blocks/CU, VGPR budget 102 (no spills).
// Power-of-2 row strides + XOR-swizzle byte^((row&7)<<4) keep ds_read_b128 at 2-way.
__global__ __launch_bounds__(256, 5) void realnvp_kernel(
    const float* __restrict__ theta, const float* __restrict__ h_g,
    const char* __restrict__ ws, float* __restrict__ out)
{
  __shared__ __align__(16) u16 hs[64 * 64];      // h tile, bf16, swizzled, stride 64
  __shared__ __align__(16) u16 hid[64 * 128];    // hidden, bf16, swizzled + col-permuted
  __shared__ __align__(16) float x_lds[64 * 4];  // current x, fp32
  __shared__ __align__(8)  float xk_lds[2 * 64]; // keep pair, [2][64] (row-pair loadable)
  __shared__ float sbuf[2 * 64 * 2];             // s/t outputs per net

  const int tid = (int)threadIdx.x;
  const int row0 = (int)blockIdx.x * 64;
  const int wv = tid >> 6, lane = tid & 63, q = lane >> 4, lr = lane & 15;
  const int mhalf = wv >> 1;                     // which 32-row half this wave computes
  const int nq = wv & 1;                         // which 64-col group (4 n-tiles)
  const char* hsB = (const char*)hs;
  char* hidB = (char*)hid;
  const int swz = (lr & 7) << 4;                 // A-frag rows have row&7 == lr&7

  // ---- stage theta -> x_lds (+ layer-0 keep pair (0,1) -> xk_lds)
  if (tid < 64) {
    float4 t4 = *(const float4*)(theta + (size_t)(row0 + tid) * 4);
    *(f32x4*)&x_lds[tid * 4] = (f32x4){t4.x, t4.y, t4.z, t4.w};
    xk_lds[tid]      = t4.x;
    xk_lds[64 + tid] = t4.y;
  }
  // ---- stage h -> hs (bf16, swizzled); thread covers a quarter row (16 cols)
  {
    int r = tid >> 2, hf = tid & 3;
    const float* src = h_g + (size_t)(row0 + r) * 64 + hf * 16;
    const int wswz = (r & 7) << 4;
#pragma unroll
    for (int c = 0; c < 16; c += 8) {
      float4 f0 = *(const float4*)(src + c);
      float4 f1 = *(const float4*)(src + c + 4);
      u32x4 o;
      o[0] = cvt_pk_bf16(f0.x, f0.y);
      o[1] = cvt_pk_bf16(f0.z, f0.w);
      o[2] = cvt_pk_bf16(f1.x, f1.y);
      o[3] = cvt_pk_bf16(f1.z, f1.w);
      *(u32x4*)((char*)hs + (((r * 64 + hf * 16 + c) * 2) ^ wswz)) = o;
    }
  }
  __syncthreads();

  float logdet = 0.0f;
  const f32x4 zero4 = {0.f, 0.f, 0.f, 0.f};
  const int col0 = nq * 64 + lr;                 // first of the wave's four 16-col tiles

  // epilogue write bases for row rl0=q*4+r within an m-tile: byte =
  // (rl0*256 + nq*128 + lr*4) ^ ((rl0&7)<<4); pair-group 1 is ^64 (XOR, not add:
  // the swizzle occupies bits 4-6). m-tile offset (bits >=12) added outside.
  unsigned wb[4];
#pragma unroll
  for (int r = 0; r < 4; ++r) {
    int rl = q * 4 + r;
    wb[r] = (unsigned)((rl * 256 + nq * 128 + lr * 4) ^ ((rl & 7) << 4));
  }

#pragma unroll 1
  for (int layer = 0; layer < 4; ++layer) {
#pragma unroll 1
    for (int net = 0; net < 2; ++net) {
      const char* base = ws + (size_t)(layer * 2 + net) * NL_STRIDE;
      const u16* w1f = (const u16*)(base + OFF_W1F);
      const u16* w2f = (const u16*)(base + OFF_W2F);
      const u16* w3f = (const u16*)(base + OFF_W3F);
      const float* w1k = (const float*)(base + OFF_W1K);
      const float* b1 = (const float*)(base + OFF_B1);
      const float* b2 = (const float*)(base + OFF_B2);
      const float* b3 = (const float*)(base + OFF_B3);

      // ================= GEMM1: hid_pre = h @ W1h  (M=64,N=128,K=64) =================
      // wave computes rows [mhalf*32, +32), cols [nq*64, +64): acc[2][4]
      f32x4 acc[2][4];
#pragma unroll
      for (int mt = 0; mt < 2; ++mt)
#pragma unroll
        for (int nt = 0; nt < 4; ++nt) acc[mt][nt] = zero4;
      __builtin_amdgcn_s_setprio(1);
#pragma unroll
      for (int kt = 0; kt < 2; ++kt) {
        const int abase = (((lr * 64 + kt * 32 + q * 8) * 2)) ^ swz;
        short8 a0 = *(const short8*)(hsB + abase + (mhalf * 2 + 0) * 2048);
        short8 a1 = *(const short8*)(hsB + abase + (mhalf * 2 + 1) * 2048);
        short8 b[4];
#pragma unroll
        for (int nt = 0; nt < 4; ++nt)
          b[nt] = *(const short8*)(w1f + (kt * 8 + nq * 4 + nt) * 512 + lane * 8);
#pragma unroll
        for (int nt = 0; nt < 4; ++nt) {
          acc[0][nt] = __builtin_amdgcn_mfma_f32_16x16x32_bf16(a0, b[nt], acc[0][nt], 0, 0, 0);
          acc[1][nt] = __builtin_amdgcn_mfma_f32_16x16x32_bf16(a1, b[nt], acc[1][nt], 0, 0, 0);
        }
      }
      __builtin_amdgcn_s_setprio(0);
      // epilogue: + keep-cols rank-2 + bias, GELU, packed -> hid (bf16 pairs)
      float wk0[4], wk1[4], bb[4];
#pragma unroll
      for (int i = 0; i < 4; ++i) {
        wk0[i] = w1k[col0 + i * 16];
        wk1[i] = w1k[128 + col0 + i * 16];
        bb[i]  = b1[col0 + i * 16];
      }
      __syncthreads();               // prior readers of hid (prev GEMM3) are done
#pragma unroll
      for (int mt = 0; mt < 2; ++mt) {
        const int moff = (mhalf * 2 + mt) * 4096;
        const int rbase = mhalf * 32 + mt * 16 + q * 4;
#pragma unroll
        for (int p = 0; p < 2; ++p) {
          int row = rbase + 2 * p;
          f32x2 xk0 = *(const f32x2*)(xk_lds + row);        // rows (row,row+1) keep0
          f32x2 xk1 = *(const f32x2*)(xk_lds + 64 + row);   // rows (row,row+1) keep1
          f32x2 g0, g1, g2, g3;
          {
            f32x2 v0 = {acc[mt][0][2 * p], acc[mt][0][2 * p + 1]};
            v0 = v0 + bc2(bb[0]); v0 = xk0 * bc2(wk0[0]) + v0; v0 = xk1 * bc2(wk1[0]) + v0;
            g0 = gelu2(v0);
            f32x2 v1 = {acc[mt][1][2 * p], acc[mt][1][2 * p + 1]};
            v1 = v1 + bc2(bb[1]); v1 = xk0 * bc2(wk0[1]) + v1; v1 = xk1 * bc2(wk1[1]) + v1;
            g1 = gelu2(v1);
            f32x2 v2 = {acc[mt][2][2 * p], acc[mt][2][2 * p + 1]};
            v2 = v2 + bc2(bb[2]); v2 = xk0 * bc2(wk0[2]) + v2; v2 = xk1 * bc2(wk1[2]) + v2;
            g2 = gelu2(v2);
            f32x2 v3 = {acc[mt][3][2 * p], acc[mt][3][2 * p + 1]};
            v3 = v3 + bc2(bb[3]); v3 = xk0 * bc2(wk0[3]) + v3; v3 = xk1 * bc2(wk1[3]) + v3;
            g3 = gelu2(v3);
          }
          unsigned w0 = wb[2 * p] + moff, w1 = wb[2 * p + 1] + moff;
          *(u32*)(hidB + w0) = cvt_pk_bf16(g0.x, g1.x);
          *(u32*)(hidB + w1) = cvt_pk_bf16(g0.y, g1.y);
          *(u32*)(hidB + (w0 ^ 64)) = cvt_pk_bf16(g2.x, g3.x);
          *(u32*)(hidB + (w1 ^ 64)) = cvt_pk_bf16(g2.y, g3.y);
        }
      }
      __syncthreads();

      // ================= GEMM2: hid = gelu(hid @ W2 + b2)  (K=128, in-place) =========
      f32x4 acc2[2][4];
#pragma unroll
      for (int mt = 0; mt < 2; ++mt)
#pragma unroll
        for (int nt = 0; nt < 4; ++nt) acc2[mt][nt] = zero4;
      __builtin_amdgcn_s_setprio(1);
#pragma unroll
      for (int kt = 0; kt < 4; ++kt) {
        const int abase = ((lr * 256 + kt * 64 + q * 16)) ^ swz;
        short8 a0 = *(const short8*)(hidB + abase + (mhalf * 2 + 0) * 4096);
        short8 a1 = *(const short8*)(hidB + abase + (mhalf * 2 + 1) * 4096);
        short8 b[4];
#pragma unroll
        for (int nt = 0; nt < 4; ++nt)
          b[nt] = *(const short8*)(w2f + (kt * 8 + nq * 4 + nt) * 512 + lane * 8);
#pragma unroll
        for (int nt = 0; nt < 4; ++nt) {
          acc2[0][nt] = __builtin_amdgcn_mfma_f32_16x16x32_bf16(a0, b[nt], acc2[0][nt], 0, 0, 0);
          acc2[1][nt] = __builtin_amdgcn_mfma_f32_16x16x32_bf16(a1, b[nt], acc2[1][nt], 0, 0, 0);
        }
      }
      __builtin_amdgcn_s_setprio(0);
      float cb[4];
#pragma unroll
      for (int i = 0; i < 4; ++i) cb[i] = b2[col0 + i * 16];
      __syncthreads();               // all reads of hid done before overwrite
#pragma unroll
      for (int mt = 0; mt < 2; ++mt) {
        const int moff = (mhalf * 2 + mt) * 4096;
#pragma unroll
        for (int p = 0; p < 2; ++p) {
          f32x2 g0, g1, g2, g3;
          {
            f32x2 v0 = {acc2[mt][0][2 * p], acc2[mt][0][2 * p + 1]};
            g0 = gelu2(v0 + bc2(cb[0]));
            f32x2 v1 = {acc2[mt][1][2 * p], acc2[mt][1][2 * p + 1]};
            g1 = gelu2(v1 + bc2(cb[1]));
            f32x2 v2 = {acc2[mt][2][2 * p], acc2[mt][2][2 * p + 1]};
            g2 = gelu2(v2 + bc2(cb[2]));
            f32x2 v3 = {acc2[mt][3][2 * p], acc2[mt][3][2 * p + 1]};
            g3 = gelu2(v3 + bc2(cb[3]));
          }
          unsigned w0 = wb[2 * p] + moff, w1 = wb[2 * p + 1] + moff;
          *(u32*)(hidB + w0) = cvt_pk_bf16(g0.x, g1.x);
          *(u32*)(hidB + w1) = cvt_pk_bf16(g0.y, g1.y);
          *(u32*)(hidB + (w0 ^ 64)) = cvt_pk_bf16(g2.x, g3.x);
          *(u32*)(hidB + (w1 ^ 64)) = cvt_pk_bf16(g2.y, g3.y);
        }
      }
      __syncthreads();

      // ================= GEMM3: s/t = hid @ W3 + b3  (N padded to 16) ================
      // wave wv covers m-tile wv, single n-tile
      f32x4 acc3 = zero4;
#pragma unroll
      for (int kt = 0; kt < 4; ++kt) {
        short8 b = *(const short8*)(w3f + kt * 512 + lane * 8);
        const int abase = ((lr * 256 + kt * 64 + q * 16)) ^ swz;
        short8 a = *(const short8*)(hidB + abase + wv * 4096);
        acc3 = __builtin_amdgcn_mfma_f32_16x16x32_bf16(a, b, acc3, 0, 0, 0);
      }
      if (lr < 2) {
        float bbv = b3[lr];
        int rb = wv * 16 + q * 4;
#pragma unroll
        for (int r = 0; r < 4; ++r)
          sbuf[net * 128 + (rb + r) * 2 + lr] = acc3[r] + bbv;
      }
      __syncthreads();
    }  // net

    // ================= coupling update =================
    if (tid < 64) {
      float s0 = sbuf[tid * 2 + 0], s1 = sbuf[tid * 2 + 1];
      float t0 = sbuf[128 + tid * 2 + 0], t1 = sbuf[128 + tid * 2 + 1];
      int a0 = (0x1002 >> (layer * 4)) & 15;     // TRANS[layer][0]
      int a1 = (0x2133 >> (layer * 4)) & 15;     // TRANS[layer][1]
      x_lds[tid * 4 + a0] = x_lds[tid * 4 + a0] * __expf(s0) + t0;
      x_lds[tid * 4 + a1] = x_lds[tid * 4 + a1] * __expf(s1) + t1;
      logdet += s0 + s1;
      // stage next layer's keep pair for the GEMM1 epilogue
      int nl_ = (layer + 1) & 3;
      int nk0 = (0x0210 >> (nl_ * 4)) & 15;      // KEEP[nl][0]
      int nk1 = (0x3321 >> (nl_ * 4)) & 15;      // KEEP[nl][1]
      xk_lds[tid]      = x_lds[tid * 4 + nk0];
      xk_lds[64 + tid] = x_lds[tid * 4 + nk1];
    }
    __syncthreads();
  }  // layer

  if (tid < 64) {
    float x0 = x_lds[tid * 4 + 0], x1 = x_lds[tid * 4 + 1];
    float x2 = x_lds[tid * 4 + 2], x3 = x_lds[tid * 4 + 3];
    out[row0 + tid] = -0.5f * (x0 * x0 + x1 * x1 + x2 * x2 + x3 * x3)
                      - 3.6757541328f + logdet;
  }
}

extern "C" void kernel_launch(void* const* d_in, const int* in_sizes, int n_in,
                              void* d_out, int out_size, void* d_ws, size_t ws_size,
                              hipStream_t stream) {
  (void)in_sizes; (void)n_in; (void)out_size; (void)ws_size;
  const float* theta = (const float*)d_in[0];
  const float* h     = (const float*)d_in[1];
  const float* sW1 = (const float*)d_in[2],  *sb1 = (const float*)d_in[3];
  const float* sW2 = (const float*)d_in[4],  *sb2 = (const float*)d_in[5];
  const float* sW3 = (const float*)d_in[6],  *sb3 = (const float*)d_in[7];
  const float* tW1 = (const float*)d_in[8],  *tb1 = (const float*)d_in[9];
  const float* tW2 = (const float*)d_in[10], *tb2 = (const float*)d_in[11];
  const float* tW3 = (const float*)d_in[12], *tb3 = (const float*)d_in[13];
  float* out = (float*)d_out;
  char* ws = (char*)d_ws;

  dim3 pgrid(8, 107);   // 8 net-layers x ceil(27138/256)
  prep_kernel<<<pgrid, 256, 0, stream>>>(sW1, sb1, sW2, sb2, sW3, sb3,
                                         tW1, tb1, tW2, tb2, tW3, tb3, ws);
  realnvp_kernel<<<8192, 256, 0, stream>>>(theta, h, (const char*)ws, out);
}

// Round 8
// 524.164 us; speedup vs baseline: 1.8846x; 1.8846x over previous
//
#include <hip/hip_runtime.h>
#include <hip/hip_bf16.h>

typedef short short8 __attribute__((ext_vector_type(8)));
typedef float f32x4 __attribute__((ext_vector_type(4)));
typedef float f32x2 __attribute__((ext_vector_type(2)));
typedef unsigned short u16;
typedef unsigned int u32;
typedef u32 u32x4 __attribute__((ext_vector_type(4)));

#define NL_STRIDE 57344
#define OFF_W1F 0
#define OFF_W2F 16384
#define OFF_W3F 49152
#define OFF_W1K 53248
#define OFF_B1  54272
#define OFF_B2  54784
#define OFF_B3  55296

__device__ __forceinline__ u16 f2bf(float f) {
  union { float f; unsigned int u; } v; v.f = f;
  unsigned int r = v.u + 0x7fffu + ((v.u >> 16) & 1u);
  return (u16)(r >> 16);
}

// packed f32x2 -> packed bf16 (RNE via MODE default). Scalar srcs: any two VGPRs.
__device__ __forceinline__ u32 cvt_pk_bf16(float lo, float hi) {
  u32 r;
  asm("v_cvt_pk_bf16_f32 %0, %1, %2" : "=v"(r) : "v"(lo), "v"(hi));
  return r;
}

__device__ __forceinline__ f32x2 bc2(float s) { return (f32x2){s, s}; }

// gelu(x) = x * Phi_approx(x); Phi ~ 0.5 + x*(p0 + p1*x^2 + p2*x^4), clamped to [0,1].
// f32x2 form lowers to v_pk_fma_f32 / v_pk_mul_f32 on gfx950.
__device__ __forceinline__ f32x2 gelu2(f32x2 x) {
  f32x2 u = x * x;
  f32x2 t = u * 0.00417617f + (-0.0560330f);
  t = t * u + 0.394326f;
  f32x2 s = x * t + 0.5f;
  s.x = __builtin_amdgcn_fmed3f(s.x, 0.0f, 1.0f);
  s.y = __builtin_amdgcn_fmed3f(s.y, 0.0f, 1.0f);
  return x * s;
}

// hid column permutation: LDS position p holds original column c(p).
// p = wv*32 + lr*2 + hi  <->  c = wv*32 + hi*16 + lr (pairs cols n and n+16 adjacently).
__device__ __forceinline__ int perm_col(int p) {
  return (p & ~31) | ((p & 1) << 4) | ((p & 31) >> 1);
}

// ---------------- prep: swizzle fp32 weights -> bf16 MFMA B-fragment order in ws ----
// B-frag layout for mfma_f32_16x16x32_bf16, tile (kt,nt): lane l holds
// B[kt*32 + (l>>4)*8 + j][nt*16 + (l&15)], j=0..7; flat elem = (kt*NT+nt)*512 + l*8 + j.
// W2/W3 K-rows are stored permuted (perm_col) to match the permuted hid layout.
__global__ __launch_bounds__(256) void prep_kernel(
    const float* __restrict__ sW1, const float* __restrict__ sb1,
    const float* __restrict__ sW2, const float* __restrict__ sb2,
    const float* __restrict__ sW3, const float* __restrict__ sb3,
    const float* __restrict__ tW1, const float* __restrict__ tb1,
    const float* __restrict__ tW2, const float* __restrict__ tb2,
    const float* __restrict__ tW3, const float* __restrict__ tb3,
    char* __restrict__ ws)
{
  int nl = blockIdx.x;               // 0..7 = layer*2 + net
  int layer = nl >> 1, net = nl & 1;
  const float* W1 = net ? tW1 : sW1;
  const float* W2 = net ? tW2 : sW2;
  const float* W3 = net ? tW3 : sW3;
  const float* B1 = net ? tb1 : sb1;
  const float* B2 = net ? tb2 : sb2;
  const float* B3 = net ? tb3 : sb3;
  char* base = ws + (size_t)nl * NL_STRIDE;
  int e = blockIdx.y * 256 + (int)threadIdx.x;

  if (e < 8192) {                                   // W1 (h-rows 2..65): K=64, N=128
    int kt = e >> 12, rem = e & 4095, nt = rem >> 9, r2 = rem & 511;
    int l = r2 >> 3, j = r2 & 7;
    int k = kt * 32 + (l >> 4) * 8 + j, n = nt * 16 + (l & 15);
    ((u16*)(base + OFF_W1F))[e] = f2bf(W1[layer * 8448 + (2 + k) * 128 + n]);
  } else if (e < 24576) {                           // W2: K=128 (perm rows), N=128
    int e2 = e - 8192;
    int kt = e2 >> 12, nt = (e2 >> 9) & 7, l = (e2 >> 3) & 63, j = e2 & 7;
    int kp = kt * 32 + (l >> 4) * 8 + j, n = nt * 16 + (l & 15);
    int c = perm_col(kp);
    ((u16*)(base + OFF_W2F))[e2] = f2bf(W2[layer * 16384 + c * 128 + n]);
  } else if (e < 26624) {                           // W3: K=128 (perm rows), N padded 2->16
    int e3 = e - 24576;
    int kt = e3 >> 9, l = (e3 >> 3) & 63, j = e3 & 7;
    int kp = kt * 32 + (l >> 4) * 8 + j, n = l & 15;
    int c = perm_col(kp);
    float v = (n < 2) ? W3[layer * 256 + c * 2 + n] : 0.0f;
    ((u16*)(base + OFF_W3F))[e3] = f2bf(v);
  } else if (e < 26880) {                           // W1 keep-rows 0..1 as fp32 [2][128]
    int e4 = e - 26624; int r = e4 >> 7, n = e4 & 127;
    ((float*)(base + OFF_W1K))[e4] = W1[layer * 8448 + r * 128 + n];
  } else if (e < 27008) {
    int e5 = e - 26880; ((float*)(base + OFF_B1))[e5] = B1[layer * 128 + e5];
  } else if (e < 27136) {
    int e6 = e - 27008; ((float*)(base + OFF_B2))[e6] = B2[layer * 128 + e6];
  } else if (e < 27138) {
    int e7 = e - 27136; ((float*)(base + OFF_B3))[e7] = B3[layer * 2 + e7];
  }
}

// ---------------- main fused kernel: 64 rows/block, 256 threads (4 waves) -----------
// EXACT Round-3 structure (the verified best: 388 us; every geometry change since
// regressed via allocator spills) with ONE delta: the barrier before the GEMM1
// epilogue is removed. It was redundant -- the previous net's GEMM3 readers of hid
// are already synchronized by that net's post-GEMM3 barrier (plus, at layer
// boundaries, the post-coupling barrier). Barriers/layer: 9 -> 7 (-22%).
// LDS 27136 B -> 5 blocks/CU; launch_bounds(256,5) VGPR budget 102, natural use ~48.
// Power-of-2 row strides + XOR-swizzle byte^((row&7)<<4) keep ds_read_b128 at 2-way.
__global__ __launch_bounds__(256, 5) void realnvp_kernel(
    const float* __restrict__ theta, const float* __restrict__ h_g,
    const char* __restrict__ ws, float* __restrict__ out)
{
  __shared__ __align__(16) u16 hs[64 * 64];      // h tile, bf16, swizzled, stride 64
  __shared__ __align__(16) u16 hid[64 * 128];    // hidden, bf16, swizzled + col-permuted
  __shared__ __align__(16) float x_lds[64 * 4];  // current x, fp32
  __shared__ __align__(8)  float xk_lds[2 * 64]; // keep pair, [2][64] (row-pair loadable)
  __shared__ float sbuf[2 * 64 * 2];             // s/t outputs per net

  const int tid = (int)threadIdx.x;
  const int row0 = (int)blockIdx.x * 64;
  const int wv = tid >> 6, lane = tid & 63, q = lane >> 4, lr = lane & 15;
  const char* hsB = (const char*)hs;
  char* hidB = (char*)hid;
  const int swz = (lr & 7) << 4;                 // A-frag rows have row&7 == lr&7

  // ---- stage theta -> x_lds (+ layer-0 keep pair (0,1) -> xk_lds)
  if (tid < 64) {
    float4 t4 = *(const float4*)(theta + (size_t)(row0 + tid) * 4);
    *(f32x4*)&x_lds[tid * 4] = (f32x4){t4.x, t4.y, t4.z, t4.w};
    xk_lds[tid]      = t4.x;
    xk_lds[64 + tid] = t4.y;
  }
  // ---- stage h -> hs (bf16, swizzled); thread covers a quarter row (16 cols)
  {
    int r = tid >> 2, hf = tid & 3;
    const float* src = h_g + (size_t)(row0 + r) * 64 + hf * 16;
    const int wswz = (r & 7) << 4;
#pragma unroll
    for (int c = 0; c < 16; c += 8) {
      float4 f0 = *(const float4*)(src + c);
      float4 f1 = *(const float4*)(src + c + 4);
      u32x4 o;
      o[0] = cvt_pk_bf16(f0.x, f0.y);
      o[1] = cvt_pk_bf16(f0.z, f0.w);
      o[2] = cvt_pk_bf16(f1.x, f1.y);
      o[3] = cvt_pk_bf16(f1.z, f1.w);
      *(u32x4*)((char*)hs + (((r * 64 + hf * 16 + c) * 2) ^ wswz)) = o;
    }
  }
  __syncthreads();

  float logdet = 0.0f;
  const f32x4 zero4 = {0.f, 0.f, 0.f, 0.f};
  const int col0 = wv * 32 + lr;                 // first of the wave's two 16-col tiles

  // epilogue write bases: pos pair (wv*32+lr*2, +1) at row q*4+r (mt*4096 added as imm)
  unsigned wb[4];
#pragma unroll
  for (int r = 0; r < 4; ++r) {
    int rl = q * 4 + r;
    wb[r] = (unsigned)((rl * 256 + wv * 64 + lr * 4) ^ ((rl & 7) << 4));
  }

#pragma unroll 1
  for (int layer = 0; layer < 4; ++layer) {
#pragma unroll 1
    for (int net = 0; net < 2; ++net) {
      const char* base = ws + (size_t)(layer * 2 + net) * NL_STRIDE;
      const u16* w1f = (const u16*)(base + OFF_W1F);
      const u16* w2f = (const u16*)(base + OFF_W2F);
      const u16* w3f = (const u16*)(base + OFF_W3F);
      const float* w1k = (const float*)(base + OFF_W1K);
      const float* b1 = (const float*)(base + OFF_B1);
      const float* b2 = (const float*)(base + OFF_B2);
      const float* b3 = (const float*)(base + OFF_B3);

      // ================= GEMM1: hid_pre = h @ W1h  (M=64,N=128,K=64) =================
      f32x4 acc[4][2];
#pragma unroll
      for (int mt = 0; mt < 4; ++mt) { acc[mt][0] = zero4; acc[mt][1] = zero4; }
      __builtin_amdgcn_s_setprio(1);
#pragma unroll
      for (int kt = 0; kt < 2; ++kt) {
        const int abase = (((lr * 64 + kt * 32 + q * 8) * 2)) ^ swz;
        short8 a[4];
#pragma unroll
        for (int mt = 0; mt < 4; ++mt)
          a[mt] = *(const short8*)(hsB + abase + mt * 2048);
        short8 b0 = *(const short8*)(w1f + (kt * 8 + wv * 2 + 0) * 512 + lane * 8);
        short8 b1v = *(const short8*)(w1f + (kt * 8 + wv * 2 + 1) * 512 + lane * 8);
#pragma unroll
        for (int mt = 0; mt < 4; ++mt) {
          acc[mt][0] = __builtin_amdgcn_mfma_f32_16x16x32_bf16(a[mt], b0, acc[mt][0], 0, 0, 0);
          acc[mt][1] = __builtin_amdgcn_mfma_f32_16x16x32_bf16(a[mt], b1v, acc[mt][1], 0, 0, 0);
        }
      }
      __builtin_amdgcn_s_setprio(0);
      // epilogue: + keep-cols rank-2 + bias, GELU, packed -> hid (bf16 pairs).
      // NO barrier needed here: prev net's GEMM3 readers of hid were synchronized
      // by the post-GEMM3 barrier (and post-coupling barrier at layer boundaries);
      // nothing since then touches hid.
      float wk00 = w1k[col0],       wk01 = w1k[col0 + 16];
      float wk10 = w1k[128 + col0], wk11 = w1k[128 + col0 + 16];
      float bb0 = b1[col0], bb1 = b1[col0 + 16];
#pragma unroll
      for (int mt = 0; mt < 4; ++mt) {
        int rb = mt * 16 + q * 4;
#pragma unroll
        for (int p = 0; p < 2; ++p) {
          int row = rb + 2 * p;
          f32x2 xk0 = *(const f32x2*)(xk_lds + row);        // rows (row,row+1) keep0
          f32x2 xk1 = *(const f32x2*)(xk_lds + 64 + row);   // rows (row,row+1) keep1
          f32x2 vA = {acc[mt][0][2 * p], acc[mt][0][2 * p + 1]};  // adjacent regs
          f32x2 vB = {acc[mt][1][2 * p], acc[mt][1][2 * p + 1]};
          vA = vA + bc2(bb0); vA = xk0 * bc2(wk00) + vA; vA = xk1 * bc2(wk10) + vA;
          vB = vB + bc2(bb1); vB = xk0 * bc2(wk01) + vB; vB = xk1 * bc2(wk11) + vB;
          f32x2 gA = gelu2(vA), gB = gelu2(vB);
          *(u32*)(hidB + (wb[2 * p]     + mt * 4096)) = cvt_pk_bf16(gA.x, gB.x);
          *(u32*)(hidB + (wb[2 * p + 1] + mt * 4096)) = cvt_pk_bf16(gA.y, gB.y);
        }
      }
      __syncthreads();               // (1) epi1 visible before GEMM2 reads

      // ================= GEMM2: hid = gelu(hid @ W2 + b2)  (K=128, in-place) =========
      f32x4 acc2[4][2];
#pragma unroll
      for (int mt = 0; mt < 4; ++mt) { acc2[mt][0] = zero4; acc2[mt][1] = zero4; }
      __builtin_amdgcn_s_setprio(1);
#pragma unroll
      for (int kt = 0; kt < 4; ++kt) {
        const int abase = ((lr * 256 + kt * 64 + q * 16)) ^ swz;
        short8 a[4];
#pragma unroll
        for (int mt = 0; mt < 4; ++mt)
          a[mt] = *(const short8*)(hidB + abase + mt * 4096);
        short8 b0 = *(const short8*)(w2f + (kt * 8 + wv * 2 + 0) * 512 + lane * 8);
        short8 b1v = *(const short8*)(w2f + (kt * 8 + wv * 2 + 1) * 512 + lane * 8);
#pragma unroll
        for (int mt = 0; mt < 4; ++mt) {
          acc2[mt][0] = __builtin_amdgcn_mfma_f32_16x16x32_bf16(a[mt], b0, acc2[mt][0], 0, 0, 0);
          acc2[mt][1] = __builtin_amdgcn_mfma_f32_16x16x32_bf16(a[mt], b1v, acc2[mt][1], 0, 0, 0);
        }
      }
      __builtin_amdgcn_s_setprio(0);
      float cb0 = b2[col0], cb1 = b2[col0 + 16];
      __syncthreads();               // (2) all reads of hid done before overwrite
#pragma unroll
      for (int mt = 0; mt < 4; ++mt) {
#pragma unroll
        for (int p = 0; p < 2; ++p) {
          f32x2 vA = {acc2[mt][0][2 * p], acc2[mt][0][2 * p + 1]};
          f32x2 vB = {acc2[mt][1][2 * p], acc2[mt][1][2 * p + 1]};
          vA = vA + bc2(cb0);
          vB = vB + bc2(cb1);
          f32x2 gA = gelu2(vA), gB = gelu2(vB);
          *(u32*)(hidB + (wb[2 * p]     + mt * 4096)) = cvt_pk_bf16(gA.x, gB.x);
          *(u32*)(hidB + (wb[2 * p + 1] + mt * 4096)) = cvt_pk_bf16(gA.y, gB.y);
        }
      }
      __syncthreads();               // (3) epi2 visible before GEMM3 reads

      // ================= GEMM3: s/t = hid @ W3 + b3  (N padded to 16) ================
      // wave wv covers m-tile wv, single n-tile
      f32x4 acc3 = zero4;
#pragma unroll
      for (int kt = 0; kt < 4; ++kt) {
        short8 b = *(const short8*)(w3f + kt * 512 + lane * 8);
        const int abase = ((lr * 256 + kt * 64 + q * 16)) ^ swz;
        short8 a = *(const short8*)(hidB + abase + wv * 4096);
        acc3 = __builtin_amdgcn_mfma_f32_16x16x32_bf16(a, b, acc3, 0, 0, 0);
      }
      if (lr < 2) {
        float bbv = b3[lr];
        int rb = wv * 16 + q * 4;
#pragma unroll
        for (int r = 0; r < 4; ++r)
          sbuf[net * 128 + (rb + r) * 2 + lr] = acc3[r] + bbv;
      }
      __syncthreads();               // (4) GEMM3 reads + sbuf writes complete
    }  // net

    // ================= coupling update =================
    if (tid < 64) {
      float s0 = sbuf[tid * 2 + 0], s1 = sbuf[tid * 2 + 1];
      float t0 = sbuf[128 + tid * 2 + 0], t1 = sbuf[128 + tid * 2 + 1];
      int a0 = (0x1002 >> (layer * 4)) & 15;     // TRANS[layer][0]
      int a1 = (0x2133 >> (layer * 4)) & 15;     // TRANS[layer][1]
      x_lds[tid * 4 + a0] = x_lds[tid * 4 + a0] * __expf(s0) + t0;
      x_lds[tid * 4 + a1] = x_lds[tid * 4 + a1] * __expf(s1) + t1;
      logdet += s0 + s1;
      // stage next layer's keep pair for the GEMM1 epilogue
      int nl_ = (layer + 1) & 3;
      int nk0 = (0x0210 >> (nl_ * 4)) & 15;      // KEEP[nl][0]
      int nk1 = (0x3321 >> (nl_ * 4)) & 15;      // KEEP[nl][1]
      xk_lds[tid]      = x_lds[tid * 4 + nk0];
      xk_lds[64 + tid] = x_lds[tid * 4 + nk1];
    }
    __syncthreads();                 // (5) x/xk ready before next layer's epi1
  }  // layer

  if (tid < 64) {
    float x0 = x_lds[tid * 4 + 0], x1 = x_lds[tid * 4 + 1];
    float x2 = x_lds[tid * 4 + 2], x3 = x_lds[tid * 4 + 3];
    out[row0 + tid] = -0.5f * (x0 * x0 + x1 * x1 + x2 * x2 + x3 * x3)
                      - 3.6757541328f + logdet;
  }
}

extern "C" void kernel_launch(void* const* d_in, const int* in_sizes, int n_in,
                              void* d_out, int out_size, void* d_ws, size_t ws_size,
                              hipStream_t stream) {
  (void)in_sizes; (void)n_in; (void)out_size; (void)ws_size;
  const float* theta = (const float*)d_in[0];
  const float* h     = (const float*)d_in[1];
  const float* sW1 = (const float*)d_in[2],  *sb1 = (const float*)d_in[3];
  const float* sW2 = (const float*)d_in[4],  *sb2 = (const float*)d_in[5];
  const float* sW3 = (const float*)d_in[6],  *sb3 = (const float*)d_in[7];
  const float* tW1 = (const float*)d_in[8],  *tb1 = (const float*)d_in[9];
  const float* tW2 = (const float*)d_in[10], *tb2 = (const float*)d_in[11];
  const float* tW3 = (const float*)d_in[12], *tb3 = (const float*)d_in[13];
  float* out = (float*)d_out;
  char* ws = (char*)d_ws;

  dim3 pgrid(8, 107);   // 8 net-layers x ceil(27138/256)
  prep_kernel<<<pgrid, 256, 0, stream>>>(sW1, sb1, sW2, sb2, sW3, sb3,
                                         tW1, tb1, tW2, tb2, tW3, tb3, ws);
  realnvp_kernel<<<8192, 256, 0, stream>>>(theta, h, (const char*)ws, out);
}